// Round 6
// baseline (261.995 us; speedup 1.0000x reference)
//
#include <hip/hip_runtime.h>
#include <stdint.h>

#define NPIX 15000
#define IMG_H 200
#define IMG_W 75
#define NVEC 3750            // NPIX / 4
#define ROWS_PER_WAVE 4
#define CHUNKS_PER_ROW 58    // 58 x 1024B = 14848 floats; remainder 152 floats/row
#define REM_START 14848      // first float of the remainder
#define REM_LANES 38         // 152 floats / 4 per lane
#define RING_FLOATS 1024     // 4 slots x 256 floats per wave

typedef float f4 __attribute__((ext_vector_type(4)));

#define GLD_LDS16(gsrc, ldst)                                                     \
    __builtin_amdgcn_global_load_lds(                                             \
        (const __attribute__((address_space(1))) void*)(gsrc),                    \
        (__attribute__((address_space(3))) void*)(ldst), 16, 0, 0)

// Pre-kernel: wp[p] = lane_W[(p%200)*75 + p/200]  (the reshape/transpose permutation)
__global__ void eb_permute_w(const float* __restrict__ lane_W, float* __restrict__ wp) {
    int p = blockIdx.x * blockDim.x + threadIdx.x;
    if (p < NPIX) {
        int w = p / IMG_H;          // 0..74
        int h = p - w * IMG_H;      // 0..199
        wp[p] = lane_W[h * IMG_W + w];
    }
}

// Phase 1: steer[b] = sum_p (rgb[b,p] > 0 ? wp[p] : 0) + lane_b
// Each wave streams 4 consecutive rows. Per row: 58 full 1KB chunks through a
// 4-slot LDS ring via global_load_lds + counted s_waitcnt vmcnt(3); the 152-float
// row remainder is accumulated up front with plain loads (so the compiler's own
// vmcnt waits never touch the pipeline). wp lives in LDS.
__global__ __launch_bounds__(256, 2) void eb_reduce(
    const float* __restrict__ rgb,       // [B, 15000]
    const float* __restrict__ wp,        // [15000] permuted lane weights
    const float* __restrict__ lane_b,    // [1]
    float* __restrict__ steer)           // [B]
{
    extern __shared__ float smem[];      // [15000] wp  +  [4 waves][1024] ring
    const int t = threadIdx.x;
    const int wave = t >> 6;
    const int lane = t & 63;

    // one-time cooperative wp fill (f4 vectorized)
    {
        const f4* __restrict__ src = reinterpret_cast<const f4*>(wp);
        f4* dst = reinterpret_cast<f4*>(smem);
        for (int i = t; i < NVEC; i += 256) dst[i] = src[i];
    }
    __syncthreads();

    const float lb = lane_b[0];

    float* ring = smem + NPIX + wave * RING_FLOATS;
    const float* gw = rgb + (size_t)(blockIdx.x * 16 + wave * ROWS_PER_WAVE) * NPIX;
    const int lane4 = lane * 4;

    // ---- remainder accumulation (consumed here; drains before the pipeline starts)
    float racc0 = 0.0f, racc1 = 0.0f, racc2 = 0.0f, racc3 = 0.0f;
    if (lane < REM_LANES) {
        f4 wr = *reinterpret_cast<const f4*>(smem + REM_START + lane4);
        f4 v0 = *reinterpret_cast<const f4*>(gw + 0 * NPIX + REM_START + lane4);
        f4 v1 = *reinterpret_cast<const f4*>(gw + 1 * NPIX + REM_START + lane4);
        f4 v2 = *reinterpret_cast<const f4*>(gw + 2 * NPIX + REM_START + lane4);
        f4 v3 = *reinterpret_cast<const f4*>(gw + 3 * NPIX + REM_START + lane4);
        racc0 = (v0.x > 0.f ? wr.x : 0.f) + (v0.y > 0.f ? wr.y : 0.f)
              + (v0.z > 0.f ? wr.z : 0.f) + (v0.w > 0.f ? wr.w : 0.f);
        racc1 = (v1.x > 0.f ? wr.x : 0.f) + (v1.y > 0.f ? wr.y : 0.f)
              + (v1.z > 0.f ? wr.z : 0.f) + (v1.w > 0.f ? wr.w : 0.f);
        racc2 = (v2.x > 0.f ? wr.x : 0.f) + (v2.y > 0.f ? wr.y : 0.f)
              + (v2.z > 0.f ? wr.z : 0.f) + (v2.w > 0.f ? wr.w : 0.f);
        racc3 = (v3.x > 0.f ? wr.x : 0.f) + (v3.y > 0.f ? wr.y : 0.f)
              + (v3.z > 0.f ? wr.z : 0.f) + (v3.w > 0.f ? wr.w : 0.f);
    }

    // ---- prologue: stage chunks (r0,c0..c2) into slots 0,1,2  (3 outstanding)
    #pragma unroll
    for (int pc = 0; pc < 3; ++pc)
        GLD_LDS16(gw + pc * 256 + lane4, ring + pc * 256);

    #pragma unroll
    for (int r = 0; r < ROWS_PER_WAVE; ++r) {
        float acc = (r == 0) ? racc0 : (r == 1) ? racc1 : (r == 2) ? racc2 : racc3;

        #pragma unroll 1
        for (int c = 0; c < CHUNKS_PER_ROW; ++c) {
            // prefetch chunk (r,c)+3, clamped at the last chunk of the stream.
            // exactly ONE issue per iteration -> FIFO depth invariant, vmcnt(3)
            // always frees exactly the chunk read below.
            int pc = c + 3, pr = r;
            if (pc >= CHUNKS_PER_ROW) { pc -= CHUNKS_PER_ROW; ++pr; }
            if (pr > ROWS_PER_WAVE - 1) { pr = ROWS_PER_WAVE - 1; pc = CHUNKS_PER_ROW - 1; }
            GLD_LDS16(gw + (size_t)pr * NPIX + pc * 256 + lane4,
                      ring + (((c + 3 + 2 * r) & 3) * 256));

            asm volatile("s_waitcnt vmcnt(3)" ::: "memory");

            f4 v = *reinterpret_cast<const f4*>(ring + (((c + 2 * r) & 3) * 256) + lane4);
            f4 w = *reinterpret_cast<const f4*>(smem + c * 256 + lane4);
            acc += (v.x > 0.f ? w.x : 0.f);
            acc += (v.y > 0.f ? w.y : 0.f);
            acc += (v.z > 0.f ? w.z : 0.f);
            acc += (v.w > 0.f ? w.w : 0.f);
        }

        // wave64 butterfly reduce (no LDS, no barrier)
        #pragma unroll
        for (int off = 32; off > 0; off >>= 1)
            acc += __shfl_down(acc, off, 64);

        if (lane == 0)
            steer[blockIdx.x * 16 + wave * ROWS_PER_WAVE + r] = acc + lb;
    }
}

// Phase 2: one thread per batch element runs the whole dueling MLP.
__global__ __launch_bounds__(256) void eb_mlp(
    const float* __restrict__ steer,     // [B]
    const float* __restrict__ distance,  // [B]
    const float* __restrict__ kmph,      // [B]
    const float* __restrict__ W1, const float* __restrict__ b1,   // [3,16],[16]
    const float* __restrict__ W2, const float* __restrict__ b2,   // [16,32],[32]
    const float* __restrict__ W3, const float* __restrict__ b3,   // [32,32],[32]
    const float* __restrict__ W4, const float* __restrict__ b4,   // [32,16],[16]
    const float* __restrict__ Wv, const float* __restrict__ bv,   // [16,1],[1]
    const float* __restrict__ Wa, const float* __restrict__ ba,   // [16,4],[4]
    float* __restrict__ out,             // [B, 4]
    int B)
{
    const int b = blockIdx.x * blockDim.x + threadIdx.x;
    if (b >= B) return;

    const float fc0 = steer[b];
    const float fc1 = distance[b];
    const float fc2 = kmph[b];

    float h1[16];
    #pragma unroll
    for (int j = 0; j < 16; ++j) {
        float s = b1[j];
        s += fc0 * W1[0 * 16 + j];
        s += fc1 * W1[1 * 16 + j];
        s += fc2 * W1[2 * 16 + j];
        h1[j] = s > 0.0f ? s : 0.0f;
    }
    float h2[32];
    #pragma unroll
    for (int j = 0; j < 32; ++j) {
        float s = b2[j];
        #pragma unroll
        for (int i = 0; i < 16; ++i) s += h1[i] * W2[i * 32 + j];
        h2[j] = s > 0.0f ? s : 0.0f;
    }
    float h3[32];
    #pragma unroll
    for (int j = 0; j < 32; ++j) {
        float s = b3[j];
        #pragma unroll
        for (int i = 0; i < 32; ++i) s += h2[i] * W3[i * 32 + j];
        h3[j] = s > 0.0f ? s : 0.0f;
    }
    float h4[16];
    #pragma unroll
    for (int j = 0; j < 16; ++j) {
        float s = b4[j];
        #pragma unroll
        for (int i = 0; i < 32; ++i) s += h3[i] * W4[i * 16 + j];
        h4[j] = s;
    }
    float value = bv[0];
    #pragma unroll
    for (int i = 0; i < 16; ++i) value += h4[i] * Wv[i];
    float a0 = ba[0], a1 = ba[1], a2 = ba[2], a3 = ba[3];
    #pragma unroll
    for (int i = 0; i < 16; ++i) {
        a0 += h4[i] * Wa[i * 4 + 0];
        a1 += h4[i] * Wa[i * 4 + 1];
        a2 += h4[i] * Wa[i * 4 + 2];
        a3 += h4[i] * Wa[i * 4 + 3];
    }
    float mean = (((a0 + a1) + a2) + a3) * 0.25f;

    float4 o;
    o.x = value + (a0 - mean);
    o.y = value + (a1 - mean);
    o.z = value + (a2 - mean);
    o.w = value + (a3 - mean);
    reinterpret_cast<float4*>(out)[b] = o;
}

extern "C" void kernel_launch(void* const* d_in, const int* in_sizes, int n_in,
                              void* d_out, int out_size, void* d_ws, size_t ws_size,
                              hipStream_t stream) {
    const float* rgb      = (const float*)d_in[0];
    const float* distance = (const float*)d_in[1];
    const float* kmph     = (const float*)d_in[2];
    const float* lane_W   = (const float*)d_in[3];
    const float* lane_b   = (const float*)d_in[4];
    const float* W1 = (const float*)d_in[5];
    const float* b1 = (const float*)d_in[6];
    const float* W2 = (const float*)d_in[7];
    const float* b2 = (const float*)d_in[8];
    const float* W3 = (const float*)d_in[9];
    const float* b3 = (const float*)d_in[10];
    const float* W4 = (const float*)d_in[11];
    const float* b4 = (const float*)d_in[12];
    const float* Wv = (const float*)d_in[13];
    const float* bv = (const float*)d_in[14];
    const float* Wa = (const float*)d_in[15];
    const float* ba = (const float*)d_in[16];

    const int B = in_sizes[1];          // distance has B elements

    float* wp    = (float*)d_ws;                 // 15000 floats = 60 KB
    float* steer = (float*)d_ws + 15104;         // [B] floats

    const size_t lds_bytes = (size_t)(NPIX + 4 * RING_FLOATS) * sizeof(float); // 76384

    eb_permute_w<<<(NPIX + 255) / 256, 256, 0, stream>>>(lane_W, wp);
    eb_reduce<<<B / 16, 256, lds_bytes, stream>>>(rgb, wp, lane_b, steer);
    eb_mlp<<<(B + 255) / 256, 256, 0, stream>>>(steer, distance, kmph,
                                                W1, b1, W2, b2, W3, b3, W4, b4,
                                                Wv, bv, Wa, ba, (float*)d_out, B);
}

// Round 7
// 151.443 us; speedup vs baseline: 1.7300x; 1.7300x over previous
//
#include <hip/hip_runtime.h>

#define NPIX 15000
#define IMG_H 200
#define IMG_W 75
#define NVEC 3750   // NPIX / 4

typedef float f4 __attribute__((ext_vector_type(4)));

// Pre-kernel: wp[p] = lane_W[(p%200)*75 + p/200]  (the reshape/transpose permutation)
__global__ void eb_permute_w(const float* __restrict__ lane_W, float* __restrict__ wp) {
    int p = blockIdx.x * blockDim.x + threadIdx.x;
    if (p < NPIX) {
        int w = p / IMG_H;          // 0..74
        int h = p - w * IMG_H;      // 0..199
        wp[p] = lane_W[h * IMG_W + w];
    }
}

__device__ __forceinline__ float sel4(f4 v, f4 w) {
    float s;
    s  = (v.x > 0.0f ? w.x : 0.0f);
    s += (v.y > 0.0f ? w.y : 0.0f);
    s += (v.z > 0.0f ? w.z : 0.0f);
    s += (v.w > 0.0f ? w.w : 0.0f);
    return s;
}

// Phase 1: steer[b] = sum_p (rgb[b,p] > 0 ? wp[p] : 0) + lane_b
// Block-per-row (R2 structure, measured best). Deep ILP: 8 rgb f4 loads in
// flight (nontemporal), then 6, then tail. 6 blocks/CU via launch_bounds.
__global__ __launch_bounds__(256, 6) void eb_reduce(
    const float* __restrict__ rgb,       // [B, 15000]
    const float* __restrict__ wp,        // [15000] permuted lane weights
    const float* __restrict__ lane_b,    // [1]
    float* __restrict__ steer)           // [B]
{
    const int b = blockIdx.x;
    const int t = threadIdx.x;

    const f4* __restrict__ row = reinterpret_cast<const f4*>(rgb + (size_t)b * NPIX);
    const f4* __restrict__ wv4 = reinterpret_cast<const f4*>(wp);

    // per-thread f4 indices: t + 256k, k=0..13 uniform; k=14 iff t < 166.
    float acc = 0.0f;
    {
        // group A: k = 0..7  (8 independent 16B nt loads back-to-back)
        f4 v0 = __builtin_nontemporal_load(&row[t]);
        f4 v1 = __builtin_nontemporal_load(&row[t +  256]);
        f4 v2 = __builtin_nontemporal_load(&row[t +  512]);
        f4 v3 = __builtin_nontemporal_load(&row[t +  768]);
        f4 v4 = __builtin_nontemporal_load(&row[t + 1024]);
        f4 v5 = __builtin_nontemporal_load(&row[t + 1280]);
        f4 v6 = __builtin_nontemporal_load(&row[t + 1536]);
        f4 v7 = __builtin_nontemporal_load(&row[t + 1792]);
        f4 w0 = wv4[t];
        f4 w1 = wv4[t +  256];
        f4 w2 = wv4[t +  512];
        f4 w3 = wv4[t +  768];
        f4 w4 = wv4[t + 1024];
        f4 w5 = wv4[t + 1280];
        f4 w6 = wv4[t + 1536];
        f4 w7 = wv4[t + 1792];
        acc += sel4(v0, w0); acc += sel4(v1, w1);
        acc += sel4(v2, w2); acc += sel4(v3, w3);
        acc += sel4(v4, w4); acc += sel4(v5, w5);
        acc += sel4(v6, w6); acc += sel4(v7, w7);
    }
    {
        // group B: k = 8..13
        f4 v0 = __builtin_nontemporal_load(&row[t + 2048]);
        f4 v1 = __builtin_nontemporal_load(&row[t + 2304]);
        f4 v2 = __builtin_nontemporal_load(&row[t + 2560]);
        f4 v3 = __builtin_nontemporal_load(&row[t + 2816]);
        f4 v4 = __builtin_nontemporal_load(&row[t + 3072]);
        f4 v5 = __builtin_nontemporal_load(&row[t + 3328]);
        f4 w0 = wv4[t + 2048];
        f4 w1 = wv4[t + 2304];
        f4 w2 = wv4[t + 2560];
        f4 w3 = wv4[t + 2816];
        f4 w4 = wv4[t + 3072];
        f4 w5 = wv4[t + 3328];
        acc += sel4(v0, w0); acc += sel4(v1, w1);
        acc += sel4(v2, w2); acc += sel4(v3, w3);
        acc += sel4(v4, w4); acc += sel4(v5, w5);
    }
    // tail: k = 14, f4 index 3584 + t, valid for t < 166
    if (t < NVEC - 3584) {
        f4 v = __builtin_nontemporal_load(&row[t + 3584]);
        f4 w = wv4[t + 3584];
        acc += sel4(v, w);
    }

    // wave64 butterfly reduce, then cross-wave via LDS
    #pragma unroll
    for (int off = 32; off > 0; off >>= 1)
        acc += __shfl_down(acc, off, 64);

    __shared__ float partial[4];
    const int wave = t >> 6;
    if ((t & 63) == 0) partial[wave] = acc;
    __syncthreads();

    if (t == 0)
        steer[b] = ((partial[0] + partial[1]) + (partial[2] + partial[3])) + lane_b[0];
}

// Phase 2: one thread per batch element runs the whole dueling MLP.
__global__ __launch_bounds__(256) void eb_mlp(
    const float* __restrict__ steer,     // [B]
    const float* __restrict__ distance,  // [B]
    const float* __restrict__ kmph,      // [B]
    const float* __restrict__ W1, const float* __restrict__ b1,   // [3,16],[16]
    const float* __restrict__ W2, const float* __restrict__ b2,   // [16,32],[32]
    const float* __restrict__ W3, const float* __restrict__ b3,   // [32,32],[32]
    const float* __restrict__ W4, const float* __restrict__ b4,   // [32,16],[16]
    const float* __restrict__ Wv, const float* __restrict__ bv,   // [16,1],[1]
    const float* __restrict__ Wa, const float* __restrict__ ba,   // [16,4],[4]
    float* __restrict__ out,             // [B, 4]
    int B)
{
    const int b = blockIdx.x * blockDim.x + threadIdx.x;
    if (b >= B) return;

    const float fc0 = steer[b];
    const float fc1 = distance[b];
    const float fc2 = kmph[b];

    float h1[16];
    #pragma unroll
    for (int j = 0; j < 16; ++j) {
        float s = b1[j];
        s += fc0 * W1[0 * 16 + j];
        s += fc1 * W1[1 * 16 + j];
        s += fc2 * W1[2 * 16 + j];
        h1[j] = s > 0.0f ? s : 0.0f;
    }
    float h2[32];
    #pragma unroll
    for (int j = 0; j < 32; ++j) {
        float s = b2[j];
        #pragma unroll
        for (int i = 0; i < 16; ++i) s += h1[i] * W2[i * 32 + j];
        h2[j] = s > 0.0f ? s : 0.0f;
    }
    float h3[32];
    #pragma unroll
    for (int j = 0; j < 32; ++j) {
        float s = b3[j];
        #pragma unroll
        for (int i = 0; i < 32; ++i) s += h2[i] * W3[i * 32 + j];
        h3[j] = s > 0.0f ? s : 0.0f;
    }
    float h4[16];
    #pragma unroll
    for (int j = 0; j < 16; ++j) {
        float s = b4[j];
        #pragma unroll
        for (int i = 0; i < 32; ++i) s += h3[i] * W4[i * 16 + j];
        h4[j] = s;
    }
    float value = bv[0];
    #pragma unroll
    for (int i = 0; i < 16; ++i) value += h4[i] * Wv[i];
    float a0 = ba[0], a1 = ba[1], a2 = ba[2], a3 = ba[3];
    #pragma unroll
    for (int i = 0; i < 16; ++i) {
        a0 += h4[i] * Wa[i * 4 + 0];
        a1 += h4[i] * Wa[i * 4 + 1];
        a2 += h4[i] * Wa[i * 4 + 2];
        a3 += h4[i] * Wa[i * 4 + 3];
    }
    float mean = (((a0 + a1) + a2) + a3) * 0.25f;

    float4 o;
    o.x = value + (a0 - mean);
    o.y = value + (a1 - mean);
    o.z = value + (a2 - mean);
    o.w = value + (a3 - mean);
    reinterpret_cast<float4*>(out)[b] = o;
}

extern "C" void kernel_launch(void* const* d_in, const int* in_sizes, int n_in,
                              void* d_out, int out_size, void* d_ws, size_t ws_size,
                              hipStream_t stream) {
    const float* rgb      = (const float*)d_in[0];
    const float* distance = (const float*)d_in[1];
    const float* kmph     = (const float*)d_in[2];
    const float* lane_W   = (const float*)d_in[3];
    const float* lane_b   = (const float*)d_in[4];
    const float* W1 = (const float*)d_in[5];
    const float* b1 = (const float*)d_in[6];
    const float* W2 = (const float*)d_in[7];
    const float* b2 = (const float*)d_in[8];
    const float* W3 = (const float*)d_in[9];
    const float* b3 = (const float*)d_in[10];
    const float* W4 = (const float*)d_in[11];
    const float* b4 = (const float*)d_in[12];
    const float* Wv = (const float*)d_in[13];
    const float* bv = (const float*)d_in[14];
    const float* Wa = (const float*)d_in[15];
    const float* ba = (const float*)d_in[16];

    const int B = in_sizes[1];          // distance has B elements

    float* wp    = (float*)d_ws;                 // 15000 floats = 60 KB
    float* steer = (float*)d_ws + 15104;         // [B] floats

    eb_permute_w<<<(NPIX + 255) / 256, 256, 0, stream>>>(lane_W, wp);
    eb_reduce<<<B, 256, 0, stream>>>(rgb, wp, lane_b, steer);
    eb_mlp<<<(B + 255) / 256, 256, 0, stream>>>(steer, distance, kmph,
                                                W1, b1, W2, b2, W3, b3, W4, b4,
                                                Wv, bv, Wa, ba, (float*)d_out, B);
}